// Round 7
// baseline (127.403 us; speedup 1.0000x reference)
//
#include <hip/hip_runtime.h>

#define B  16
#define S  4096
#define R  512          // LORA_RANK
#define QR 1536        // Q_LORA_RANK
#define H  32
#define D  128
#define HD 4096        // H*D
#define SC 128         // s-chunk per block
#define CH 32          // S/SC

using f32x4 = __attribute__((ext_vector_type(4))) float;
using s16x8 = __attribute__((ext_vector_type(8))) short;

union bfu { s16x8 v; uint u[4]; };

__device__ __forceinline__ ushort bf_hi(float x) {
  return (ushort)(__float_as_uint(x) >> 16);        // truncation
}
__device__ __forceinline__ float hi_f(float x) {    // fp32 value of truncated-bf16
  return __uint_as_float(__float_as_uint(x) & 0xFFFF0000u);
}
__device__ __forceinline__ uint pack_hi2(float x, float y) {  // [bf16(x) | bf16(y)<<16], trunc
  return (__float_as_uint(x) >> 16) | (__float_as_uint(y) & 0xFFFF0000u);
}
__device__ __forceinline__ ushort f2bf_rne(float x) {
  uint u = __float_as_uint(x);
  return (ushort)((u + 0x7FFFu + ((u >> 16) & 1u)) >> 16);
}
__device__ __forceinline__ float bf2f(ushort u) {
  return __uint_as_float((uint)u << 16);
}

// ---------------------------------------------------------------------------
// Kernel A: q[b,o] = hsq[b,:] . Wq[o,:] + bq[o]
// ---------------------------------------------------------------------------
__global__ __launch_bounds__(512) void k_q(const float* __restrict__ hsq,
                                           const float* __restrict__ Wq,
                                           const float* __restrict__ bq,
                                           float* __restrict__ q) {
  __shared__ float hs[B * QR];  // 96 KiB
  int tid = threadIdx.x;
  for (int idx = tid * 4; idx < B * QR; idx += 2048)
    *(float4*)&hs[idx] = *(const float4*)&hsq[idx];
  __syncthreads();

  int wave = tid >> 6, lane = tid & 63;
  int o = blockIdx.x * 16 + wave * 2;

  float acc0[B], acc1[B];
#pragma unroll
  for (int b = 0; b < B; ++b) { acc0[b] = 0.f; acc1[b] = 0.f; }

  const float* w0r = Wq + (size_t)o * QR;
  const float* w1r = w0r + QR;
  for (int k = lane * 4; k < QR; k += 256) {
    float4 wa = *(const float4*)&w0r[k];
    float4 wb = *(const float4*)&w1r[k];
#pragma unroll
    for (int b = 0; b < B; ++b) {
      float4 h4 = *(const float4*)&hs[b * QR + k];
      acc0[b] += wa.x * h4.x + wa.y * h4.y + wa.z * h4.z + wa.w * h4.w;
      acc1[b] += wb.x * h4.x + wb.y * h4.y + wb.z * h4.z + wb.w * h4.w;
    }
  }
#pragma unroll
  for (int b = 0; b < B; ++b) {
    float v0 = acc0[b], v1 = acc1[b];
#pragma unroll
    for (int off = 32; off > 0; off >>= 1) {
      v0 += __shfl_xor(v0, off);
      v1 += __shfl_xor(v1, off);
    }
    if (lane == 0) {
      q[b * HD + o]     = v0 + bq[o];
      q[b * HD + o + 1] = v1 + bq[o + 1];
    }
  }
}

// ---------------------------------------------------------------------------
// Kernel B: qhat[b,h,r] = sum_d q[b, h*D+d] * Wkv[h*D+d, r]
// Emits bf16 hi/lo split directly (k-contiguous, A-fragment-ready).
// ---------------------------------------------------------------------------
__global__ __launch_bounds__(256) void k_qhat(const float* __restrict__ q,
                                              const float* __restrict__ Wkv,
                                              ushort* __restrict__ qhi,
                                              ushort* __restrict__ qlo) {
  int h = blockIdx.x;
  int r0 = blockIdx.y * 64;
  __shared__ float qs[B][D];
  int tid = threadIdx.x;
  for (int idx = tid; idx < B * D; idx += 256) {
    int b = idx >> 7, d = idx & (D - 1);
    qs[b][d] = q[b * HD + h * D + d];
  }
  __syncthreads();

  int r_l = tid & 63, bg = tid >> 6;
  float acc[4] = {0.f, 0.f, 0.f, 0.f};
  const float* wbase = Wkv + (size_t)(h * D) * R + r0 + r_l;
  for (int d = 0; d < D; d += 4) {
    float w0 = wbase[(d + 0) * R];
    float w1 = wbase[(d + 1) * R];
    float w2 = wbase[(d + 2) * R];
    float w3 = wbase[(d + 3) * R];
#pragma unroll
    for (int i = 0; i < 4; ++i) {
      float4 q4 = *(const float4*)&qs[bg * 4 + i][d];
      acc[i] += q4.x * w0 + q4.y * w1 + q4.z * w2 + q4.w * w3;
    }
  }
#pragma unroll
  for (int i = 0; i < 4; ++i) {
    size_t idx = ((size_t)(bg * 4 + i) * H + h) * R + r0 + r_l;
    qhi[idx] = bf_hi(acc[i]);
    qlo[idx] = bf_hi(acc[i] - hi_f(acc[i]));
  }
}

// ---------------------------------------------------------------------------
// Fused MFMA flash kernel v3. grid (B, CH) x 512 threads (8 waves).
// Phase 1 (BARRIER-FREE): each wave stages ITS OWN 16 s-rows of the ckv k-tile
//   into a single 32KB fp32 LDS tile (XOR-swizzled 16B blocks), depth-2
//   register double-buffer for the staging loads (counted vmcnt by compiler,
//   no barrier drains). B-frags: fp32 LDS read + hi/lo bf16 split in reg.
//   A-frags: direct 16B global loads of pre-split qhi/qlo (L2-hot).
//   Split-bf16 QK^T: 3 MFMAs (hi*hi + hi*lo + lo*hi) = fp32-grade logits.
// softmax: register + cross-wave LDS reduce (2 barriers, the only ones).
// Phase 2 (BARRIER-FREE): A = ckv^T frags via 8 scalar dword loads/lane from
//   global (L2/L3-hot re-read), trunc-bf16; B = P from swizzled Ps LDS.
//   Each wave owns a 64-r slab. part stored bf16.
// q.bkv logit term is constant per (b,h) -> cancels in softmax.
// ---------------------------------------------------------------------------
__global__ __launch_bounds__(512, 4) void k_fmha(const ushort* __restrict__ qhi,
                                                 const ushort* __restrict__ qlo,
                                                 const float* __restrict__ ckv,
                                                 ushort* __restrict__ part,
                                                 float* __restrict__ mbuf,
                                                 float* __restrict__ lbuf) {
  __shared__ __align__(16) float csA[SC * 64];   // 32 KB fp32 [s][16B-blk swz]
  __shared__ __align__(16) ushort Ps[H * 128];   // 8 KB bf16 P, swizzled
  __shared__ float red[512];                     // [0,256): max, [256,512): sum

  const int b = blockIdx.x, chunk = blockIdx.y;
  const int tid = threadIdx.x;
  const int lane = tid & 63, wv = tid >> 6;
  const int lcol = lane & 15, lgrp = lane >> 4;

  const float* cbase = ckv + ((size_t)b * S + (size_t)chunk * SC) * R;
  const ushort* qh_b = qhi + (size_t)b * H * R;
  const ushort* ql_b = qlo + (size_t)b * H * R;

  f32x4 acc[2];
  acc[0] = {0.f, 0.f, 0.f, 0.f};
  acc[1] = {0.f, 0.f, 0.f, 0.f};

  // ---- staging geometry: wave wv owns s-rows [16wv, 16wv+16) ----
  const int ss  = 16 * wv + (lane >> 2);   // staged row for this lane
  const int kb0 = (lane & 3) * 4;          // first 16B-block (of 16) staged
  const int sx  = ss & 7;                  // row swizzle key
  const float* srow = cbase + (size_t)ss * R;
  float* lrow = &csA[ss * 64];

  const int sfr = 16 * wv + lcol;          // B-fragment row
  const int fx  = sfr & 7;
  const float* frow = &csA[sfr * 64];

  // ---------------- phase 1: QK^T (no barriers) ----------------
  float4 v[2][4];
#pragma unroll
  for (int j = 0; j < 4; ++j) v[0][j] = *(const float4*)&srow[4 * (kb0 + j)];
#pragma unroll
  for (int j = 0; j < 4; ++j) v[1][j] = *(const float4*)&srow[64 + 4 * (kb0 + j)];

#pragma unroll
  for (int t = 0; t < 8; ++t) {
    // commit tile t to LDS (swizzled): LDS blk jb holds src blk jb^(s&7)
#pragma unroll
    for (int j = 0; j < 4; ++j)
      *(float4*)&lrow[4 * ((kb0 + j) ^ sx)] = v[t & 1][j];
    if (t + 2 < 8) {
#pragma unroll
      for (int j = 0; j < 4; ++j)
        v[t & 1][j] = *(const float4*)&srow[64 * (t + 2) + 4 * (kb0 + j)];
    }
#pragma unroll
    for (int ks = 0; ks < 2; ++ks) {
      const int kb = 2 * lgrp + 8 * ks;
      float4 fa = *(const float4*)&frow[4 * (kb ^ fx)];
      float4 fb = *(const float4*)&frow[4 * ((kb + 1) ^ fx)];
      bfu bh, bl;
      bh.u[0] = pack_hi2(fa.x, fa.y); bh.u[1] = pack_hi2(fa.z, fa.w);
      bh.u[2] = pack_hi2(fb.x, fb.y); bh.u[3] = pack_hi2(fb.z, fb.w);
      bl.u[0] = pack_hi2(fa.x - hi_f(fa.x), fa.y - hi_f(fa.y));
      bl.u[1] = pack_hi2(fa.z - hi_f(fa.z), fa.w - hi_f(fa.w));
      bl.u[2] = pack_hi2(fb.x - hi_f(fb.x), fb.y - hi_f(fb.y));
      bl.u[3] = pack_hi2(fb.z - hi_f(fb.z), fb.w - hi_f(fb.w));
      const size_t ko = (size_t)(64 * t + 32 * ks + 8 * lgrp);
#pragma unroll
      for (int mt = 0; mt < 2; ++mt) {
        const size_t moff = (size_t)(16 * mt + lcol) * R + ko;
        s16x8 ah = *(const s16x8*)&qh_b[moff];
        s16x8 al = *(const s16x8*)&ql_b[moff];
        acc[mt] = __builtin_amdgcn_mfma_f32_16x16x32_bf16(ah, bh.v, acc[mt], 0, 0, 0);
        acc[mt] = __builtin_amdgcn_mfma_f32_16x16x32_bf16(ah, bl.v, acc[mt], 0, 0, 0);
        acc[mt] = __builtin_amdgcn_mfma_f32_16x16x32_bf16(al, bh.v, acc[mt], 0, 0, 0);
      }
    }
  }

  // ---------------- softmax ----------------
  // D layout: h = 16*mt + 4*lgrp + i ; s = 16*wv + lcol
  float pm[2][4];
#pragma unroll
  for (int mt = 0; mt < 2; ++mt)
#pragma unroll
    for (int i = 0; i < 4; ++i) pm[mt][i] = acc[mt][i];
#pragma unroll
  for (int off = 1; off <= 8; off <<= 1)
#pragma unroll
    for (int mt = 0; mt < 2; ++mt)
#pragma unroll
      for (int i = 0; i < 4; ++i)
        pm[mt][i] = fmaxf(pm[mt][i], __shfl_xor(pm[mt][i], off));
  if (lcol == 0) {
#pragma unroll
    for (int mt = 0; mt < 2; ++mt)
#pragma unroll
      for (int i = 0; i < 4; ++i)
        red[(16 * mt + 4 * lgrp + i) * 8 + wv] = pm[mt][i];
  }
  __syncthreads();

  float e_[2][4], psum[2][4];
#pragma unroll
  for (int mt = 0; mt < 2; ++mt)
#pragma unroll
    for (int i = 0; i < 4; ++i) {
      int h = 16 * mt + 4 * lgrp + i;
      float4 r0 = *(float4*)&red[h * 8];
      float4 r1 = *(float4*)&red[h * 8 + 4];
      float m = fmaxf(fmaxf(fmaxf(r0.x, r0.y), fmaxf(r0.z, r0.w)),
                      fmaxf(fmaxf(r1.x, r1.y), fmaxf(r1.z, r1.w)));
      float e = __expf(acc[mt][i] - m);
      e_[mt][i] = e;
      psum[mt][i] = e;
    }
#pragma unroll
  for (int off = 1; off <= 8; off <<= 1)
#pragma unroll
    for (int mt = 0; mt < 2; ++mt)
#pragma unroll
      for (int i = 0; i < 4; ++i)
        psum[mt][i] += __shfl_xor(psum[mt][i], off);
  if (lcol == 0) {
#pragma unroll
    for (int mt = 0; mt < 2; ++mt)
#pragma unroll
      for (int i = 0; i < 4; ++i)
        red[256 + (16 * mt + 4 * lgrp + i) * 8 + wv] = psum[mt][i];
  }
  // P -> Ps (bf16, swizzled)
#pragma unroll
  for (int mt = 0; mt < 2; ++mt)
#pragma unroll
    for (int i = 0; i < 4; ++i) {
      int h = 16 * mt + 4 * lgrp + i;
      int s = 16 * wv + lcol;
      Ps[h * 128 + (((s >> 3) ^ (h & 7)) << 3) + (s & 7)] = f2bf_rne(e_[mt][i]);
    }
  __syncthreads();

  if (wv == 0 && lcol == 0) {
#pragma unroll
    for (int mt = 0; mt < 2; ++mt)
#pragma unroll
      for (int i = 0; i < 4; ++i) {
        int h = 16 * mt + 4 * lgrp + i;
        float4 r0 = *(float4*)&red[h * 8];
        float4 r1 = *(float4*)&red[h * 8 + 4];
        float M = fmaxf(fmaxf(fmaxf(r0.x, r0.y), fmaxf(r0.z, r0.w)),
                        fmaxf(fmaxf(r1.x, r1.y), fmaxf(r1.z, r1.w)));
        float4 l0 = *(float4*)&red[256 + h * 8];
        float4 l1 = *(float4*)&red[256 + h * 8 + 4];
        float L = (l0.x + l0.y + l0.z + l0.w) + (l1.x + l1.y + l1.z + l1.w);
        mbuf[((size_t)b * CH + chunk) * H + h] = M;
        lbuf[((size_t)b * CH + chunk) * H + h] = L;
      }
  }

  // ---------------- phase 2: part = P . ckv (no barriers) ----------------
  s16x8 bp[4][2];
#pragma unroll
  for (int kt4 = 0; kt4 < 4; ++kt4)
#pragma unroll
    for (int nt = 0; nt < 2; ++nt) {
      int h = 16 * nt + lcol;
      int kb = 4 * kt4 + lgrp;
      bp[kt4][nt] = *(const s16x8*)&Ps[h * 128 + ((kb ^ (h & 7)) << 3)];
    }

  ushort* pb = part + (size_t)(b * CH + chunk) * H * R;
#pragma unroll
  for (int mtr = 0; mtr < 4; ++mtr) {
    const int r = 64 * wv + 16 * mtr + lcol;   // A row (m = lcol within 16)
    const float* colp = cbase + r;
    f32x4 a0 = {0.f, 0.f, 0.f, 0.f}, a1 = {0.f, 0.f, 0.f, 0.f};
#pragma unroll
    for (int kt4 = 0; kt4 < 4; ++kt4) {
      float f[8];
#pragma unroll
      for (int j = 0; j < 8; ++j)
        f[j] = colp[(size_t)(32 * kt4 + 8 * lgrp + j) * R];
      bfu a2;
      a2.u[0] = pack_hi2(f[0], f[1]); a2.u[1] = pack_hi2(f[2], f[3]);
      a2.u[2] = pack_hi2(f[4], f[5]); a2.u[3] = pack_hi2(f[6], f[7]);
      a0 = __builtin_amdgcn_mfma_f32_16x16x32_bf16(a2.v, bp[kt4][0], a0, 0, 0, 0);
      a1 = __builtin_amdgcn_mfma_f32_16x16x32_bf16(a2.v, bp[kt4][1], a1, 0, 0, 0);
    }
    const int rg0 = 64 * wv + 16 * mtr + 4 * lgrp;  // D rows rg0..rg0+3
    uint2 w0 = {pack_hi2(a0[0], a0[1]), pack_hi2(a0[2], a0[3])};
    uint2 w1 = {pack_hi2(a1[0], a1[1]), pack_hi2(a1[2], a1[3])};
    *(uint2*)&pb[(size_t)lcol * R + rg0]        = w0;  // h = lcol      (nt=0)
    *(uint2*)&pb[(size_t)(16 + lcol) * R + rg0] = w1;  // h = 16 + lcol (nt=1)
  }
}

// ---------------------------------------------------------------------------
// Combine: ctx[b,h,r] = sum_c e^{m_c-M} part[b,c,h,r] / sum_c e^{m_c-M} l_c
// ---------------------------------------------------------------------------
__global__ __launch_bounds__(256) void k_combine(const ushort* __restrict__ part,
                                                 const float* __restrict__ mbuf,
                                                 const float* __restrict__ lbuf,
                                                 float* __restrict__ ctx) {
  const int bid = blockIdx.x;
  const int b = bid >> 5, h = bid & 31;
  const int tid = threadIdx.x;
  float mv[CH], wv[CH];
  float M = -3.0e38f;
#pragma unroll
  for (int c = 0; c < CH; ++c) {
    mv[c] = mbuf[((size_t)b * CH + c) * H + h];
    M = fmaxf(M, mv[c]);
  }
  float denom = 0.f;
#pragma unroll
  for (int c = 0; c < CH; ++c) {
    wv[c] = __expf(mv[c] - M);
    denom += wv[c] * lbuf[((size_t)b * CH + c) * H + h];
  }
  const float inv = 1.f / denom;
  float s0 = 0.f, s1 = 0.f;
#pragma unroll
  for (int c = 0; c < CH; ++c) {
    const ushort* pp = part + (((size_t)b * CH + c) * H + h) * R;
    s0 += wv[c] * bf2f(pp[tid]);
    s1 += wv[c] * bf2f(pp[tid + 256]);
  }
  ctx[((size_t)b * H + h) * R + tid] = s0 * inv;
  ctx[((size_t)b * H + h) * R + tid + 256] = s1 * inv;
}

// ---------------------------------------------------------------------------
// Kernel F2: out[b, h*D+d] = Wkv[h*D+d,:] . ctx[b,h,:] + bkv[h*D+d]
// ---------------------------------------------------------------------------
__global__ __launch_bounds__(256) void k_out(const float* __restrict__ ctx,
                                             const float* __restrict__ Wkv,
                                             const float* __restrict__ bkv,
                                             float* __restrict__ out) {
  int h = blockIdx.x;
  int d0 = blockIdx.y * 32;
  __shared__ float cs[B][R];  // 32 KiB
  int tid = threadIdx.x;
  for (int idx = tid * 4; idx < B * R; idx += 1024) {
    int b = idx >> 9, r = idx & 511;
    *(float4*)&cs[b][r] = *(const float4*)&ctx[(size_t)(b * H + h) * R + r];
  }
  __syncthreads();

  int dg = tid & 31;
  int bg = tid >> 5;
  int d = d0 + dg;
  int b0 = bg * 2;
  float acc0 = 0.f, acc1 = 0.f;
  const float* wrow = Wkv + ((size_t)(h * D + d)) * R;
  for (int i = 0; i < R; i += 4) {
    float4 w4 = *(const float4*)&wrow[i];
    float4 ca = *(const float4*)&cs[b0][i];
    float4 cb = *(const float4*)&cs[b0 + 1][i];
    acc0 += w4.x * ca.x + w4.y * ca.y + w4.z * ca.z + w4.w * ca.w;
    acc1 += w4.x * cb.x + w4.y * cb.y + w4.z * cb.z + w4.w * cb.w;
  }
  float bv = bkv[h * D + d];
  out[(size_t)b0 * HD + h * D + d]       = acc0 + bv;
  out[(size_t)(b0 + 1) * HD + h * D + d] = acc1 + bv;
}

// ---------------------------------------------------------------------------
extern "C" void kernel_launch(void* const* d_in, const int* in_sizes, int n_in,
                              void* d_out, int out_size, void* d_ws, size_t ws_size,
                              hipStream_t stream) {
  (void)in_sizes; (void)n_in; (void)out_size; (void)ws_size;
  const float* hsq = (const float*)d_in[0];
  const float* ckv = (const float*)d_in[1];
  const float* Wq  = (const float*)d_in[2];
  const float* bq  = (const float*)d_in[3];
  const float* Wkv = (const float*)d_in[4];
  const float* bkv = (const float*)d_in[5];
  float* out = (float*)d_out;

  float* ws   = (float*)d_ws;
  float* q    = ws;                          // 65536 f
  float* ctx  = q + 65536;                   // 262144 f
  float* mbuf = ctx + 262144;                // 16384 f
  float* lbuf = mbuf + 16384;                // 16384 f
  ushort* qhi  = (ushort*)(lbuf + 16384);    // 262144 us
  ushort* qlo  = qhi + 262144;               // 262144 us
  ushort* part = qlo + 262144;               // 8388608 us (16 MB)

  k_q<<<256, 512, 0, stream>>>(hsq, Wq, bq, q);
  k_qhat<<<dim3(32, 8), 256, 0, stream>>>(q, Wkv, qhi, qlo);
  k_fmha<<<dim3(B, CH), 512, 0, stream>>>(qhi, qlo, ckv, part, mbuf, lbuf);
  k_combine<<<B * H, 256, 0, stream>>>(part, mbuf, lbuf, ctx);
  k_out<<<dim3(32, 4), 256, 0, stream>>>(ctx, Wkv, bkv, out);
}

// Round 8
// 91.821 us; speedup vs baseline: 1.3875x; 1.3875x over previous
//
#include <hip/hip_runtime.h>

#define B  16
#define S  4096
#define R  512          // LORA_RANK
#define QR 1536         // Q_LORA_RANK
#define H  32
#define D  128
#define HD 4096         // H*D
#define SC 128          // s-chunk per block
#define CH 32           // S/SC
#define KT 32           // phase-1 k-tile
#define NT1 16          // R/KT

using f32x4 = __attribute__((ext_vector_type(4))) float;
using s16x8 = __attribute__((ext_vector_type(8))) short;
union bfu { s16x8 v; uint u[4]; };

typedef const void __attribute__((address_space(1)))* gas_t;
typedef void __attribute__((address_space(3)))* las_t;

__device__ __forceinline__ void gload16(const void* g, void* l) {
  __builtin_amdgcn_global_load_lds((gas_t)g, (las_t)l, 16, 0, 0);
}
__device__ __forceinline__ ushort bf_hi(float x) {
  return (ushort)(__float_as_uint(x) >> 16);        // truncation
}
__device__ __forceinline__ float hi_f(float x) {
  return __uint_as_float(__float_as_uint(x) & 0xFFFF0000u);
}
__device__ __forceinline__ uint pack_hi2(float x, float y) {  // [bf16(x)|bf16(y)<<16]
  return (__float_as_uint(x) >> 16) | (__float_as_uint(y) & 0xFFFF0000u);
}
__device__ __forceinline__ ushort f2bf_rne(float x) {
  uint u = __float_as_uint(x);
  return (ushort)((u + 0x7FFFu + ((u >> 16) & 1u)) >> 16);
}
__device__ __forceinline__ float bf2f(ushort u) {
  return __uint_as_float((uint)u << 16);
}

// ---------------------------------------------------------------------------
// Kernel A: q[b,o] = hsq[b,:] . Wq[o,:] + bq[o]
// ---------------------------------------------------------------------------
__global__ __launch_bounds__(512) void k_q(const float* __restrict__ hsq,
                                           const float* __restrict__ Wq,
                                           const float* __restrict__ bq,
                                           float* __restrict__ q) {
  __shared__ float hs[B * QR];  // 96 KiB
  int tid = threadIdx.x;
  for (int idx = tid * 4; idx < B * QR; idx += 2048)
    *(float4*)&hs[idx] = *(const float4*)&hsq[idx];
  __syncthreads();

  int wave = tid >> 6, lane = tid & 63;
  int o = blockIdx.x * 16 + wave * 2;

  float acc0[B], acc1[B];
#pragma unroll
  for (int b = 0; b < B; ++b) { acc0[b] = 0.f; acc1[b] = 0.f; }

  const float* w0r = Wq + (size_t)o * QR;
  const float* w1r = w0r + QR;
  for (int k = lane * 4; k < QR; k += 256) {
    float4 wa = *(const float4*)&w0r[k];
    float4 wb = *(const float4*)&w1r[k];
#pragma unroll
    for (int b = 0; b < B; ++b) {
      float4 h4 = *(const float4*)&hs[b * QR + k];
      acc0[b] += wa.x * h4.x + wa.y * h4.y + wa.z * h4.z + wa.w * h4.w;
      acc1[b] += wb.x * h4.x + wb.y * h4.y + wb.z * h4.z + wb.w * h4.w;
    }
  }
#pragma unroll
  for (int b = 0; b < B; ++b) {
    float v0 = acc0[b], v1 = acc1[b];
#pragma unroll
    for (int off = 32; off > 0; off >>= 1) {
      v0 += __shfl_xor(v0, off);
      v1 += __shfl_xor(v1, off);
    }
    if (lane == 0) {
      q[b * HD + o]     = v0 + bq[o];
      q[b * HD + o + 1] = v1 + bq[o + 1];
    }
  }
}

// ---------------------------------------------------------------------------
// Kernel B: qhat = q . Wkv per head, emitted as bf16 hi/lo split (k-major).
// ---------------------------------------------------------------------------
__global__ __launch_bounds__(256) void k_qhat(const float* __restrict__ q,
                                              const float* __restrict__ Wkv,
                                              ushort* __restrict__ qhi,
                                              ushort* __restrict__ qlo) {
  int h = blockIdx.x;
  int r0 = blockIdx.y * 64;
  __shared__ float qs[B][D];
  int tid = threadIdx.x;
  for (int idx = tid; idx < B * D; idx += 256) {
    int b = idx >> 7, d = idx & (D - 1);
    qs[b][d] = q[b * HD + h * D + d];
  }
  __syncthreads();

  int r_l = tid & 63, bg = tid >> 6;
  float acc[4] = {0.f, 0.f, 0.f, 0.f};
  const float* wbase = Wkv + (size_t)(h * D) * R + r0 + r_l;
  for (int d = 0; d < D; d += 4) {
    float w0 = wbase[(d + 0) * R];
    float w1 = wbase[(d + 1) * R];
    float w2 = wbase[(d + 2) * R];
    float w3 = wbase[(d + 3) * R];
#pragma unroll
    for (int i = 0; i < 4; ++i) {
      float4 q4 = *(const float4*)&qs[bg * 4 + i][d];
      acc[i] += q4.x * w0 + q4.y * w1 + q4.z * w2 + q4.w * w3;
    }
  }
#pragma unroll
  for (int i = 0; i < 4; ++i) {
    size_t idx = ((size_t)(bg * 4 + i) * H + h) * R + r0 + r_l;
    qhi[idx] = bf_hi(acc[i]);
    qlo[idx] = bf_hi(acc[i] - hi_f(acc[i]));
  }
}

// ---------------------------------------------------------------------------
// Fused MFMA flash kernel v4. grid (B, CH) x 512 threads (8 waves), 2 blk/CU.
// Phase 1: ckv + qhat(hi/lo) k-tiles staged via global_load_lds (width 16),
//   pre-swizzled SOURCE + linear LDS dest (XOR involution on 16B blocks),
//   double-buffered, one __syncthreads per tile. Split-bf16 QK^T (3 MFMAs).
// softmax: register + cross-wave LDS reduce; P -> Ps bf16 swizzled.
// Phase 2: row-major ckv re-read (L3-hot), reg-staged + write-late (T14) into
//   swizzled transposed bf16 tile (dbuf in phase-1 LDS region); PV MFMAs.
// q.bkv logit term cancels in softmax.
// ---------------------------------------------------------------------------
__global__ __launch_bounds__(512, 4) void k_fmha(const ushort* __restrict__ qhi,
                                                 const ushort* __restrict__ qlo,
                                                 const float* __restrict__ ckv,
                                                 ushort* __restrict__ part,
                                                 float* __restrict__ mbuf,
                                                 float* __restrict__ lbuf) {
  __shared__ __align__(16) float  csA[2][4096];   // 2 x 16KB: [128s][32k] (16B-blk swz)
  __shared__ __align__(16) ushort qs[2][2048];    // 2 x 4KB: [32h][blk: hi 0-3, lo 4-7]
  __shared__ __align__(16) ushort Ps[H * 128];    // 8KB
  __shared__ float red[512];                      // 2KB

  const int b = blockIdx.x, chunk = blockIdx.y;
  const int tid = threadIdx.x;
  const int lane = tid & 63, wv = tid >> 6;
  const int lcol = lane & 15, lgrp = lane >> 4;

  const float* cbase = ckv + ((size_t)b * S + (size_t)chunk * SC) * R;
  const ushort* qh_b = qhi + (size_t)b * H * R;
  const ushort* ql_b = qlo + (size_t)b * H * R;

  f32x4 acc[2];
  acc[0] = {0.f, 0.f, 0.f, 0.f};
  acc[1] = {0.f, 0.f, 0.f, 0.f};

  // ---------------- phase 1 staging (gload_lds, pre-swizzled source) --------
  auto STAGE1 = [&](int bufsel, int kt) {
#pragma unroll
    for (int i = 0; i < 2; ++i) {
      int u = tid + 512 * i;
      int s = u >> 3;                 // 0..127
      int jb = u & 7;                 // dest 16B block
      int sb = jb ^ (s & 7);          // source k-block (involution)
      gload16(cbase + (size_t)s * R + kt + 4 * sb, &csA[bufsel][u * 4]);
    }
    if (tid < 256) {
      int h = tid >> 3;               // 0..31
      int jb = tid & 7;               // dest block
      int lg = jb ^ (h & 7);          // logical: 0-3 = hi k-blk, 4-7 = lo k-blk
      const ushort* src = (lg < 4 ? qh_b : ql_b) + (size_t)h * R + kt + 8 * (lg & 3);
      gload16(src, &qs[bufsel][tid * 8]);
    }
  };

  auto COMPUTE1 = [&](int bufsel) {
    const int srow = 16 * wv + lcol;
    const int bkey = srow & 7;
    const float* brow = &csA[bufsel][srow * 32];
    float4 fa = *(const float4*)&brow[4 * ((2 * lgrp) ^ bkey)];
    float4 fb = *(const float4*)&brow[4 * ((2 * lgrp + 1) ^ bkey)];
    bfu bh, bl;
    bh.u[0] = pack_hi2(fa.x, fa.y); bh.u[1] = pack_hi2(fa.z, fa.w);
    bh.u[2] = pack_hi2(fb.x, fb.y); bh.u[3] = pack_hi2(fb.z, fb.w);
    bl.u[0] = pack_hi2(fa.x - hi_f(fa.x), fa.y - hi_f(fa.y));
    bl.u[1] = pack_hi2(fa.z - hi_f(fa.z), fa.w - hi_f(fa.w));
    bl.u[2] = pack_hi2(fb.x - hi_f(fb.x), fb.y - hi_f(fb.y));
    bl.u[3] = pack_hi2(fb.z - hi_f(fb.z), fb.w - hi_f(fb.w));
#pragma unroll
    for (int mt = 0; mt < 2; ++mt) {
      const int h = 16 * mt + lcol;
      const int hkey = h & 7;
      const ushort* qrow = &qs[bufsel][h * 64];
      s16x8 ah = *(const s16x8*)&qrow[8 * (lgrp ^ hkey)];
      s16x8 al = *(const s16x8*)&qrow[8 * ((4 + lgrp) ^ hkey)];
      acc[mt] = __builtin_amdgcn_mfma_f32_16x16x32_bf16(ah, bh.v, acc[mt], 0, 0, 0);
      acc[mt] = __builtin_amdgcn_mfma_f32_16x16x32_bf16(ah, bl.v, acc[mt], 0, 0, 0);
      acc[mt] = __builtin_amdgcn_mfma_f32_16x16x32_bf16(al, bh.v, acc[mt], 0, 0, 0);
    }
  };

  STAGE1(0, 0);
  __syncthreads();
#pragma unroll
  for (int t = 0; t < NT1; ++t) {
    if (t + 1 < NT1) STAGE1((t + 1) & 1, (t + 1) * KT);
    COMPUTE1(t & 1);
    __syncthreads();
  }

  // ---------------- softmax ----------------
  // D layout: h = 16*mt + 4*lgrp + i ; s = 16*wv + lcol
  float pm[2][4];
#pragma unroll
  for (int mt = 0; mt < 2; ++mt)
#pragma unroll
    for (int i = 0; i < 4; ++i) pm[mt][i] = acc[mt][i];
#pragma unroll
  for (int off = 1; off <= 8; off <<= 1)
#pragma unroll
    for (int mt = 0; mt < 2; ++mt)
#pragma unroll
      for (int i = 0; i < 4; ++i)
        pm[mt][i] = fmaxf(pm[mt][i], __shfl_xor(pm[mt][i], off));
  if (lcol == 0) {
#pragma unroll
    for (int mt = 0; mt < 2; ++mt)
#pragma unroll
      for (int i = 0; i < 4; ++i)
        red[(16 * mt + 4 * lgrp + i) * 8 + wv] = pm[mt][i];
  }
  __syncthreads();

  float e_[2][4], psum[2][4];
#pragma unroll
  for (int mt = 0; mt < 2; ++mt)
#pragma unroll
    for (int i = 0; i < 4; ++i) {
      int h = 16 * mt + 4 * lgrp + i;
      float4 r0 = *(float4*)&red[h * 8];
      float4 r1 = *(float4*)&red[h * 8 + 4];
      float m = fmaxf(fmaxf(fmaxf(r0.x, r0.y), fmaxf(r0.z, r0.w)),
                      fmaxf(fmaxf(r1.x, r1.y), fmaxf(r1.z, r1.w)));
      float e = __expf(acc[mt][i] - m);
      e_[mt][i] = e;
      psum[mt][i] = e;
    }
#pragma unroll
  for (int off = 1; off <= 8; off <<= 1)
#pragma unroll
    for (int mt = 0; mt < 2; ++mt)
#pragma unroll
      for (int i = 0; i < 4; ++i)
        psum[mt][i] += __shfl_xor(psum[mt][i], off);
  if (lcol == 0) {
#pragma unroll
    for (int mt = 0; mt < 2; ++mt)
#pragma unroll
      for (int i = 0; i < 4; ++i)
        red[256 + (16 * mt + 4 * lgrp + i) * 8 + wv] = psum[mt][i];
  }
#pragma unroll
  for (int mt = 0; mt < 2; ++mt)
#pragma unroll
    for (int i = 0; i < 4; ++i) {
      int h = 16 * mt + 4 * lgrp + i;
      int s = 16 * wv + lcol;
      Ps[h * 128 + (((s >> 3) ^ (h & 7)) << 3) + (s & 7)] = f2bf_rne(e_[mt][i]);
    }
  __syncthreads();

  if (wv == 0 && lcol == 0) {
#pragma unroll
    for (int mt = 0; mt < 2; ++mt)
#pragma unroll
      for (int i = 0; i < 4; ++i) {
        int h = 16 * mt + 4 * lgrp + i;
        float4 r0 = *(float4*)&red[h * 8];
        float4 r1 = *(float4*)&red[h * 8 + 4];
        float M = fmaxf(fmaxf(fmaxf(r0.x, r0.y), fmaxf(r0.z, r0.w)),
                        fmaxf(fmaxf(r1.x, r1.y), fmaxf(r1.z, r1.w)));
        float4 l0 = *(float4*)&red[256 + h * 8];
        float4 l1 = *(float4*)&red[256 + h * 8 + 4];
        float L = (l0.x + l0.y + l0.z + l0.w) + (l1.x + l1.y + l1.z + l1.w);
        mbuf[((size_t)b * CH + chunk) * H + h] = M;
        lbuf[((size_t)b * CH + chunk) * H + h] = L;
      }
  }

  // ---------------- phase 2: part = P . ckv ----------------
  const int nt = wv & 1, mtr = wv >> 1;  // n-tile (h), m-tile (r within 64)
  s16x8 bp[4];
#pragma unroll
  for (int k4 = 0; k4 < 4; ++k4) {
    int h = 16 * nt + lcol;
    int kb = 4 * k4 + lgrp;
    bp[k4] = *(const s16x8*)&Ps[h * 128 + ((kb ^ (h & 7)) << 3)];
  }

  ushort* cs2 = (ushort*)&csA[0][0];    // 2 x 8192 ushorts ([64r][128s] swz)
  const int sblk = tid >> 5;            // 0..15 (8-s block)
  const int rr = tid & 31;              // r and r+32 handled per thread
  float fA[8], fB[8];
  ushort* pb2 = part + (size_t)(b * CH + chunk) * H * R;

  auto LOAD2 = [&](int rt) {
    const float* base = cbase + (size_t)(8 * sblk) * R + rt * 64 + rr;
#pragma unroll
    for (int j = 0; j < 8; ++j) {
      fA[j] = base[(size_t)j * R];
      fB[j] = base[(size_t)j * R + 32];
    }
  };
  auto WRITE2 = [&](int bufsel) {
    ushort* t2 = cs2 + bufsel * 8192;
    uint4 pa, pbv;
    pa.x = pack_hi2(fA[0], fA[1]); pa.y = pack_hi2(fA[2], fA[3]);
    pa.z = pack_hi2(fA[4], fA[5]); pa.w = pack_hi2(fA[6], fA[7]);
    pbv.x = pack_hi2(fB[0], fB[1]); pbv.y = pack_hi2(fB[2], fB[3]);
    pbv.z = pack_hi2(fB[4], fB[5]); pbv.w = pack_hi2(fB[6], fB[7]);
    *(uint4*)&t2[(size_t)rr * 128 + 8 * (sblk ^ (rr & 7))] = pa;
    *(uint4*)&t2[(size_t)(rr + 32) * 128 + 8 * (sblk ^ ((rr + 32) & 7))] = pbv;
  };
  auto COMPUTE2 = [&](int bufsel, int rt) {
    const ushort* t2 = cs2 + bufsel * 8192;
    const int rl = 16 * mtr + lcol;
    const int rk = rl & 7;
    f32x4 a2 = {0.f, 0.f, 0.f, 0.f};
#pragma unroll
    for (int k4 = 0; k4 < 4; ++k4) {
      s16x8 av = *(const s16x8*)&t2[(size_t)rl * 128 + 8 * ((4 * k4 + lgrp) ^ rk)];
      a2 = __builtin_amdgcn_mfma_f32_16x16x32_bf16(av, bp[k4], a2, 0, 0, 0);
    }
    uint2 w2;
    w2.x = pack_hi2(a2[0], a2[1]);
    w2.y = pack_hi2(a2[2], a2[3]);
    const int rg = rt * 64 + 16 * mtr + 4 * lgrp;
    *(uint2*)&pb2[(size_t)(16 * nt + lcol) * R + rg] = w2;
  };

  LOAD2(0);
  WRITE2(0);
  __syncthreads();
#pragma unroll
  for (int rt = 0; rt < 8; ++rt) {
    if (rt < 7) LOAD2(rt + 1);
    COMPUTE2(rt & 1, rt);
    if (rt < 7) WRITE2((rt + 1) & 1);
    __syncthreads();
  }
}

// ---------------------------------------------------------------------------
// Combine: ctx[b,h,r] = sum_c e^{m_c-M} part[b,c,h,r] / sum_c e^{m_c-M} l_c
// ---------------------------------------------------------------------------
__global__ __launch_bounds__(256) void k_combine(const ushort* __restrict__ part,
                                                 const float* __restrict__ mbuf,
                                                 const float* __restrict__ lbuf,
                                                 float* __restrict__ ctx) {
  const int bid = blockIdx.x;
  const int b = bid >> 5, h = bid & 31;
  const int tid = threadIdx.x;
  float mv[CH], wv[CH];
  float M = -3.0e38f;
#pragma unroll
  for (int c = 0; c < CH; ++c) {
    mv[c] = mbuf[((size_t)b * CH + c) * H + h];
    M = fmaxf(M, mv[c]);
  }
  float denom = 0.f;
#pragma unroll
  for (int c = 0; c < CH; ++c) {
    wv[c] = __expf(mv[c] - M);
    denom += wv[c] * lbuf[((size_t)b * CH + c) * H + h];
  }
  const float inv = 1.f / denom;
  float s0 = 0.f, s1 = 0.f;
#pragma unroll
  for (int c = 0; c < CH; ++c) {
    const ushort* pp = part + (((size_t)b * CH + c) * H + h) * R;
    s0 += wv[c] * bf2f(pp[tid]);
    s1 += wv[c] * bf2f(pp[tid + 256]);
  }
  ctx[((size_t)b * H + h) * R + tid] = s0 * inv;
  ctx[((size_t)b * H + h) * R + tid + 256] = s1 * inv;
}

// ---------------------------------------------------------------------------
// Kernel F2: out[b, h*D+d] = Wkv[h*D+d,:] . ctx[b,h,:] + bkv[h*D+d]
// ---------------------------------------------------------------------------
__global__ __launch_bounds__(256) void k_out(const float* __restrict__ ctx,
                                             const float* __restrict__ Wkv,
                                             const float* __restrict__ bkv,
                                             float* __restrict__ out) {
  int h = blockIdx.x;
  int d0 = blockIdx.y * 32;
  __shared__ float cs[B][R];  // 32 KiB
  int tid = threadIdx.x;
  for (int idx = tid * 4; idx < B * R; idx += 1024) {
    int b = idx >> 9, r = idx & 511;
    *(float4*)&cs[b][r] = *(const float4*)&ctx[(size_t)(b * H + h) * R + r];
  }
  __syncthreads();

  int dg = tid & 31;
  int bg = tid >> 5;
  int d = d0 + dg;
  int b0 = bg * 2;
  float acc0 = 0.f, acc1 = 0.f;
  const float* wrow = Wkv + ((size_t)(h * D + d)) * R;
  for (int i = 0; i < R; i += 4) {
    float4 w4 = *(const float4*)&wrow[i];
    float4 ca = *(const float4*)&cs[b0][i];
    float4 cb = *(const float4*)&cs[b0 + 1][i];
    acc0 += w4.x * ca.x + w4.y * ca.y + w4.z * ca.z + w4.w * ca.w;
    acc1 += w4.x * cb.x + w4.y * cb.y + w4.z * cb.z + w4.w * cb.w;
  }
  float bv = bkv[h * D + d];
  out[(size_t)b0 * HD + h * D + d]       = acc0 + bv;
  out[(size_t)(b0 + 1) * HD + h * D + d] = acc1 + bv;
}

// ---------------------------------------------------------------------------
extern "C" void kernel_launch(void* const* d_in, const int* in_sizes, int n_in,
                              void* d_out, int out_size, void* d_ws, size_t ws_size,
                              hipStream_t stream) {
  (void)in_sizes; (void)n_in; (void)out_size; (void)ws_size;
  const float* hsq = (const float*)d_in[0];
  const float* ckv = (const float*)d_in[1];
  const float* Wq  = (const float*)d_in[2];
  const float* bq  = (const float*)d_in[3];
  const float* Wkv = (const float*)d_in[4];
  const float* bkv = (const float*)d_in[5];
  float* out = (float*)d_out;

  float* ws   = (float*)d_ws;
  float* q    = ws;                          // 65536 f
  float* ctx  = q + 65536;                   // 262144 f
  float* mbuf = ctx + 262144;                // 16384 f
  float* lbuf = mbuf + 16384;                // 16384 f
  ushort* qhi  = (ushort*)(lbuf + 16384);    // 262144 us
  ushort* qlo  = qhi + 262144;               // 262144 us
  ushort* part = qlo + 262144;               // 8388608 us (16 MB)

  k_q<<<256, 512, 0, stream>>>(hsq, Wq, bq, q);
  k_qhat<<<dim3(32, 8), 256, 0, stream>>>(q, Wkv, qhi, qlo);
  k_fmha<<<dim3(B, CH), 512, 0, stream>>>(qhi, qlo, ckv, part, mbuf, lbuf);
  k_combine<<<B * H, 256, 0, stream>>>(part, mbuf, lbuf, ctx);
  k_out<<<dim3(32, 4), 256, 0, stream>>>(ctx, Wkv, bkv, out);
}

// Round 9
// 91.517 us; speedup vs baseline: 1.3921x; 1.0033x over previous
//
#include <hip/hip_runtime.h>

#define B  16
#define S  4096
#define R  512          // LORA_RANK
#define QR 1536         // Q_LORA_RANK
#define H  32
#define D  128
#define HD 4096         // H*D
#define SC 128          // s-chunk per block
#define CH 32           // S/SC
#define KT 32           // phase-1 k-tile
#define NT1 16          // R/KT

using f32x4 = __attribute__((ext_vector_type(4))) float;
using s16x8 = __attribute__((ext_vector_type(8))) short;
union bfu { s16x8 v; uint u[4]; };

typedef const void __attribute__((address_space(1)))* gas_t;
typedef void __attribute__((address_space(3)))* las_t;

__device__ __forceinline__ void gload16(const void* g, void* l) {
  __builtin_amdgcn_global_load_lds((gas_t)g, (las_t)l, 16, 0, 0);
}
__device__ __forceinline__ ushort bf_hi(float x) {
  return (ushort)(__float_as_uint(x) >> 16);        // truncation
}
__device__ __forceinline__ float hi_f(float x) {
  return __uint_as_float(__float_as_uint(x) & 0xFFFF0000u);
}
__device__ __forceinline__ uint pack_hi2(float x, float y) {  // [bf16(x)|bf16(y)<<16]
  return (__float_as_uint(x) >> 16) | (__float_as_uint(y) & 0xFFFF0000u);
}
__device__ __forceinline__ ushort f2bf_rne(float x) {
  uint u = __float_as_uint(x);
  return (ushort)((u + 0x7FFFu + ((u >> 16) & 1u)) >> 16);
}
__device__ __forceinline__ float bf2f(ushort u) {
  return __uint_as_float((uint)u << 16);
}

// ---------------------------------------------------------------------------
// Kernel A: q[b,o] = hsq[b,:] . Wq[o,:] + bq[o]
// ---------------------------------------------------------------------------
__global__ __launch_bounds__(512) void k_q(const float* __restrict__ hsq,
                                           const float* __restrict__ Wq,
                                           const float* __restrict__ bq,
                                           float* __restrict__ q) {
  __shared__ float hs[B * QR];  // 96 KiB
  int tid = threadIdx.x;
  for (int idx = tid * 4; idx < B * QR; idx += 2048)
    *(float4*)&hs[idx] = *(const float4*)&hsq[idx];
  __syncthreads();

  int wave = tid >> 6, lane = tid & 63;
  int o = blockIdx.x * 16 + wave * 2;

  float acc0[B], acc1[B];
#pragma unroll
  for (int b = 0; b < B; ++b) { acc0[b] = 0.f; acc1[b] = 0.f; }

  const float* w0r = Wq + (size_t)o * QR;
  const float* w1r = w0r + QR;
  for (int k = lane * 4; k < QR; k += 256) {
    float4 wa = *(const float4*)&w0r[k];
    float4 wb = *(const float4*)&w1r[k];
#pragma unroll
    for (int b = 0; b < B; ++b) {
      float4 h4 = *(const float4*)&hs[b * QR + k];
      acc0[b] += wa.x * h4.x + wa.y * h4.y + wa.z * h4.z + wa.w * h4.w;
      acc1[b] += wb.x * h4.x + wb.y * h4.y + wb.z * h4.z + wb.w * h4.w;
    }
  }
#pragma unroll
  for (int b = 0; b < B; ++b) {
    float v0 = acc0[b], v1 = acc1[b];
#pragma unroll
    for (int off = 32; off > 0; off >>= 1) {
      v0 += __shfl_xor(v0, off);
      v1 += __shfl_xor(v1, off);
    }
    if (lane == 0) {
      q[b * HD + o]     = v0 + bq[o];
      q[b * HD + o + 1] = v1 + bq[o + 1];
    }
  }
}

// ---------------------------------------------------------------------------
// Kernel B: qhat = q . Wkv per head, emitted as bf16 hi/lo split (k-major).
// ---------------------------------------------------------------------------
__global__ __launch_bounds__(256) void k_qhat(const float* __restrict__ q,
                                              const float* __restrict__ Wkv,
                                              ushort* __restrict__ qhi,
                                              ushort* __restrict__ qlo) {
  int h = blockIdx.x;
  int r0 = blockIdx.y * 64;
  __shared__ float qs[B][D];
  int tid = threadIdx.x;
  for (int idx = tid; idx < B * D; idx += 256) {
    int b = idx >> 7, d = idx & (D - 1);
    qs[b][d] = q[b * HD + h * D + d];
  }
  __syncthreads();

  int r_l = tid & 63, bg = tid >> 6;
  float acc[4] = {0.f, 0.f, 0.f, 0.f};
  const float* wbase = Wkv + (size_t)(h * D) * R + r0 + r_l;
  for (int d = 0; d < D; d += 4) {
    float w0 = wbase[(d + 0) * R];
    float w1 = wbase[(d + 1) * R];
    float w2 = wbase[(d + 2) * R];
    float w3 = wbase[(d + 3) * R];
#pragma unroll
    for (int i = 0; i < 4; ++i) {
      float4 q4 = *(const float4*)&qs[bg * 4 + i][d];
      acc[i] += q4.x * w0 + q4.y * w1 + q4.z * w2 + q4.w * w3;
    }
  }
#pragma unroll
  for (int i = 0; i < 4; ++i) {
    size_t idx = ((size_t)(bg * 4 + i) * H + h) * R + r0 + r_l;
    qhi[idx] = bf_hi(acc[i]);
    qlo[idx] = bf_hi(acc[i] - hi_f(acc[i]));
  }
}

// ---------------------------------------------------------------------------
// Fused MFMA flash kernel v5. grid (B, CH) x 512 threads (8 waves), 2 blk/CU.
// Phase 1: TRIPLE-buffered gload_lds staging (pre-swizzled source, linear LDS
//   dest), counted `s_waitcnt vmcnt(2)` + raw s_barrier per tile — loads for
//   2 tiles always in flight, no vmcnt(0) sawtooth. Split-bf16 QK^T.
// softmax: register + cross-wave LDS reduce; P -> Ps bf16 swizzled.
// Phase 2: row-major ckv re-read (L3-hot), reg-staged write-late into
//   swizzled transposed bf16 tile (dbuf aliased onto csA); PV MFMAs.
// q.bkv logit term cancels in softmax.
// ---------------------------------------------------------------------------
__global__ __launch_bounds__(512, 4) void k_fmha(const ushort* __restrict__ qhi,
                                                 const ushort* __restrict__ qlo,
                                                 const float* __restrict__ ckv,
                                                 ushort* __restrict__ part,
                                                 float* __restrict__ mbuf,
                                                 float* __restrict__ lbuf) {
  __shared__ __align__(16) float  csA[3][4096];   // 3 x 16KB: [128s][32k] swz
  __shared__ __align__(16) ushort qs[3][2048];    // 3 x 4KB: [32h][hi:0-3|lo:4-7]
  __shared__ __align__(16) ushort Ps[H * 128];    // 8KB
  __shared__ float red[512];                      // 2KB   (total 70KB)

  const int b = blockIdx.x, chunk = blockIdx.y;
  const int tid = threadIdx.x;
  const int lane = tid & 63, wv = tid >> 6;
  const int lcol = lane & 15, lgrp = lane >> 4;

  const float* cbase = ckv + ((size_t)b * S + (size_t)chunk * SC) * R;
  const ushort* qh_b = qhi + (size_t)b * H * R;
  const ushort* ql_b = qlo + (size_t)b * H * R;

  f32x4 acc[2];
  acc[0] = {0.f, 0.f, 0.f, 0.f};
  acc[1] = {0.f, 0.f, 0.f, 0.f};

  // ---------------- phase 1 staging (gload_lds, pre-swizzled source) --------
  auto STAGE1 = [&](int bufsel, int kt) {
#pragma unroll
    for (int i = 0; i < 2; ++i) {
      int u = tid + 512 * i;
      int s = u >> 3;                 // 0..127
      int jb = u & 7;                 // dest 16B block
      int sb = jb ^ (s & 7);          // source k-block (involution)
      gload16(cbase + (size_t)s * R + kt + 4 * sb, &csA[bufsel][u * 4]);
    }
    if (tid < 256) {                  // waves 0-3 only (wave-uniform branch)
      int h = tid >> 3;               // 0..31
      int jb = tid & 7;               // dest block
      int lg = jb ^ (h & 7);          // logical: 0-3 = hi k-blk, 4-7 = lo k-blk
      const ushort* src = (lg < 4 ? qh_b : ql_b) + (size_t)h * R + kt + 8 * (lg & 3);
      gload16(src, &qs[bufsel][tid * 8]);
    }
  };

  auto COMPUTE1 = [&](int bufsel) {
    const int srow = 16 * wv + lcol;
    const int bkey = srow & 7;
    const float* brow = &csA[bufsel][srow * 32];
    float4 fa = *(const float4*)&brow[4 * ((2 * lgrp) ^ bkey)];
    float4 fb = *(const float4*)&brow[4 * ((2 * lgrp + 1) ^ bkey)];
    bfu bh, bl;
    bh.u[0] = pack_hi2(fa.x, fa.y); bh.u[1] = pack_hi2(fa.z, fa.w);
    bh.u[2] = pack_hi2(fb.x, fb.y); bh.u[3] = pack_hi2(fb.z, fb.w);
    bl.u[0] = pack_hi2(fa.x - hi_f(fa.x), fa.y - hi_f(fa.y));
    bl.u[1] = pack_hi2(fa.z - hi_f(fa.z), fa.w - hi_f(fa.w));
    bl.u[2] = pack_hi2(fb.x - hi_f(fb.x), fb.y - hi_f(fb.y));
    bl.u[3] = pack_hi2(fb.z - hi_f(fb.z), fb.w - hi_f(fb.w));
#pragma unroll
    for (int mt = 0; mt < 2; ++mt) {
      const int h = 16 * mt + lcol;
      const int hkey = h & 7;
      const ushort* qrow = &qs[bufsel][h * 64];
      s16x8 ah = *(const s16x8*)&qrow[8 * (lgrp ^ hkey)];
      s16x8 al = *(const s16x8*)&qrow[8 * ((4 + lgrp) ^ hkey)];
      acc[mt] = __builtin_amdgcn_mfma_f32_16x16x32_bf16(ah, bh.v, acc[mt], 0, 0, 0);
      acc[mt] = __builtin_amdgcn_mfma_f32_16x16x32_bf16(ah, bl.v, acc[mt], 0, 0, 0);
      acc[mt] = __builtin_amdgcn_mfma_f32_16x16x32_bf16(al, bh.v, acc[mt], 0, 0, 0);
    }
  };

  // prologue: 2 tiles in flight
  STAGE1(0, 0);
  STAGE1(1, KT);
#pragma unroll
  for (int t = 0; t < NT1; ++t) {
    // tile t landed when <=2 newest (tile t+1's) VMEM instrs remain outstanding
    if (t < NT1 - 1) {
      asm volatile("s_waitcnt vmcnt(2)" ::: "memory");
    } else {
      asm volatile("s_waitcnt vmcnt(0)" ::: "memory");
    }
    __builtin_amdgcn_sched_barrier(0);
    __builtin_amdgcn_s_barrier();
    COMPUTE1(t % 3);
    if (t + 2 < NT1) STAGE1((t + 2) % 3, (t + 2) * KT);
  }

  // ---------------- softmax ----------------
  // D layout: h = 16*mt + 4*lgrp + i ; s = 16*wv + lcol
  float pm[2][4];
#pragma unroll
  for (int mt = 0; mt < 2; ++mt)
#pragma unroll
    for (int i = 0; i < 4; ++i) pm[mt][i] = acc[mt][i];
#pragma unroll
  for (int off = 1; off <= 8; off <<= 1)
#pragma unroll
    for (int mt = 0; mt < 2; ++mt)
#pragma unroll
      for (int i = 0; i < 4; ++i)
        pm[mt][i] = fmaxf(pm[mt][i], __shfl_xor(pm[mt][i], off));
  if (lcol == 0) {
#pragma unroll
    for (int mt = 0; mt < 2; ++mt)
#pragma unroll
      for (int i = 0; i < 4; ++i)
        red[(16 * mt + 4 * lgrp + i) * 8 + wv] = pm[mt][i];
  }
  __syncthreads();

  float e_[2][4], psum[2][4];
#pragma unroll
  for (int mt = 0; mt < 2; ++mt)
#pragma unroll
    for (int i = 0; i < 4; ++i) {
      int h = 16 * mt + 4 * lgrp + i;
      float4 r0 = *(float4*)&red[h * 8];
      float4 r1 = *(float4*)&red[h * 8 + 4];
      float m = fmaxf(fmaxf(fmaxf(r0.x, r0.y), fmaxf(r0.z, r0.w)),
                      fmaxf(fmaxf(r1.x, r1.y), fmaxf(r1.z, r1.w)));
      float e = __expf(acc[mt][i] - m);
      e_[mt][i] = e;
      psum[mt][i] = e;
    }
#pragma unroll
  for (int off = 1; off <= 8; off <<= 1)
#pragma unroll
    for (int mt = 0; mt < 2; ++mt)
#pragma unroll
      for (int i = 0; i < 4; ++i)
        psum[mt][i] += __shfl_xor(psum[mt][i], off);
  if (lcol == 0) {
#pragma unroll
    for (int mt = 0; mt < 2; ++mt)
#pragma unroll
      for (int i = 0; i < 4; ++i)
        red[256 + (16 * mt + 4 * lgrp + i) * 8 + wv] = psum[mt][i];
  }
#pragma unroll
  for (int mt = 0; mt < 2; ++mt)
#pragma unroll
    for (int i = 0; i < 4; ++i) {
      int h = 16 * mt + 4 * lgrp + i;
      int s = 16 * wv + lcol;
      Ps[h * 128 + (((s >> 3) ^ (h & 7)) << 3) + (s & 7)] = f2bf_rne(e_[mt][i]);
    }
  __syncthreads();

  if (wv == 0 && lcol == 0) {
#pragma unroll
    for (int mt = 0; mt < 2; ++mt)
#pragma unroll
      for (int i = 0; i < 4; ++i) {
        int h = 16 * mt + 4 * lgrp + i;
        float4 r0 = *(float4*)&red[h * 8];
        float4 r1 = *(float4*)&red[h * 8 + 4];
        float M = fmaxf(fmaxf(fmaxf(r0.x, r0.y), fmaxf(r0.z, r0.w)),
                        fmaxf(fmaxf(r1.x, r1.y), fmaxf(r1.z, r1.w)));
        float4 l0 = *(float4*)&red[256 + h * 8];
        float4 l1 = *(float4*)&red[256 + h * 8 + 4];
        float L = (l0.x + l0.y + l0.z + l0.w) + (l1.x + l1.y + l1.z + l1.w);
        mbuf[((size_t)b * CH + chunk) * H + h] = M;
        lbuf[((size_t)b * CH + chunk) * H + h] = L;
      }
  }

  // ---------------- phase 2: part = P . ckv ----------------
  const int nt = wv & 1, mtr = wv >> 1;  // n-tile (h), m-tile (r within 64)
  s16x8 bp[4];
#pragma unroll
  for (int k4 = 0; k4 < 4; ++k4) {
    int h = 16 * nt + lcol;
    int kb = 4 * k4 + lgrp;
    bp[k4] = *(const s16x8*)&Ps[h * 128 + ((kb ^ (h & 7)) << 3)];
  }

  ushort* cs2 = (ushort*)&csA[0][0];    // 2 x 8192 ushorts ([64r][128s] swz)
  const int sblk = tid >> 5;            // 0..15 (8-s block)
  const int rr = tid & 31;              // r and r+32 handled per thread
  float fA[8], fB[8];
  ushort* pb2 = part + (size_t)(b * CH + chunk) * H * R;

  auto LOAD2 = [&](int rt) {
    const float* base = cbase + (size_t)(8 * sblk) * R + rt * 64 + rr;
#pragma unroll
    for (int j = 0; j < 8; ++j) {
      fA[j] = base[(size_t)j * R];
      fB[j] = base[(size_t)j * R + 32];
    }
  };
  auto WRITE2 = [&](int bufsel) {
    ushort* t2 = cs2 + bufsel * 8192;
    uint4 pa, pbv;
    pa.x = pack_hi2(fA[0], fA[1]); pa.y = pack_hi2(fA[2], fA[3]);
    pa.z = pack_hi2(fA[4], fA[5]); pa.w = pack_hi2(fA[6], fA[7]);
    pbv.x = pack_hi2(fB[0], fB[1]); pbv.y = pack_hi2(fB[2], fB[3]);
    pbv.z = pack_hi2(fB[4], fB[5]); pbv.w = pack_hi2(fB[6], fB[7]);
    *(uint4*)&t2[(size_t)rr * 128 + 8 * (sblk ^ (rr & 7))] = pa;
    *(uint4*)&t2[(size_t)(rr + 32) * 128 + 8 * (sblk ^ ((rr + 32) & 7))] = pbv;
  };
  auto COMPUTE2 = [&](int bufsel, int rt) {
    const ushort* t2 = cs2 + bufsel * 8192;
    const int rl = 16 * mtr + lcol;
    const int rk = rl & 7;
    f32x4 a2 = {0.f, 0.f, 0.f, 0.f};
#pragma unroll
    for (int k4 = 0; k4 < 4; ++k4) {
      s16x8 av = *(const s16x8*)&t2[(size_t)rl * 128 + 8 * ((4 * k4 + lgrp) ^ rk)];
      a2 = __builtin_amdgcn_mfma_f32_16x16x32_bf16(av, bp[k4], a2, 0, 0, 0);
    }
    uint2 w2;
    w2.x = pack_hi2(a2[0], a2[1]);
    w2.y = pack_hi2(a2[2], a2[3]);
    const int rg = rt * 64 + 16 * mtr + 4 * lgrp;
    *(uint2*)&pb2[(size_t)(16 * nt + lcol) * R + rg] = w2;
  };

  LOAD2(0);
  WRITE2(0);
  __syncthreads();
#pragma unroll
  for (int rt = 0; rt < 8; ++rt) {
    if (rt < 7) LOAD2(rt + 1);
    COMPUTE2(rt & 1, rt);
    if (rt < 7) WRITE2((rt + 1) & 1);
    __syncthreads();
  }
}

// ---------------------------------------------------------------------------
// Combine: ctx[b,h,r] = sum_c e^{m_c-M} part[b,c,h,r] / sum_c e^{m_c-M} l_c
// ---------------------------------------------------------------------------
__global__ __launch_bounds__(256) void k_combine(const ushort* __restrict__ part,
                                                 const float* __restrict__ mbuf,
                                                 const float* __restrict__ lbuf,
                                                 float* __restrict__ ctx) {
  const int bid = blockIdx.x;
  const int b = bid >> 5, h = bid & 31;
  const int tid = threadIdx.x;
  float mv[CH], wv[CH];
  float M = -3.0e38f;
#pragma unroll
  for (int c = 0; c < CH; ++c) {
    mv[c] = mbuf[((size_t)b * CH + c) * H + h];
    M = fmaxf(M, mv[c]);
  }
  float denom = 0.f;
#pragma unroll
  for (int c = 0; c < CH; ++c) {
    wv[c] = __expf(mv[c] - M);
    denom += wv[c] * lbuf[((size_t)b * CH + c) * H + h];
  }
  const float inv = 1.f / denom;
  float s0 = 0.f, s1 = 0.f;
#pragma unroll
  for (int c = 0; c < CH; ++c) {
    const ushort* pp = part + (((size_t)b * CH + c) * H + h) * R;
    s0 += wv[c] * bf2f(pp[tid]);
    s1 += wv[c] * bf2f(pp[tid + 256]);
  }
  ctx[((size_t)b * H + h) * R + tid] = s0 * inv;
  ctx[((size_t)b * H + h) * R + tid + 256] = s1 * inv;
}

// ---------------------------------------------------------------------------
// Kernel F2: out[b, h*D+d] = Wkv[h*D+d,:] . ctx[b,h,:] + bkv[h*D+d]
// ---------------------------------------------------------------------------
__global__ __launch_bounds__(256) void k_out(const float* __restrict__ ctx,
                                             const float* __restrict__ Wkv,
                                             const float* __restrict__ bkv,
                                             float* __restrict__ out) {
  int h = blockIdx.x;
  int d0 = blockIdx.y * 32;
  __shared__ float cs[B][R];  // 32 KiB
  int tid = threadIdx.x;
  for (int idx = tid * 4; idx < B * R; idx += 1024) {
    int b = idx >> 9, r = idx & 511;
    *(float4*)&cs[b][r] = *(const float4*)&ctx[(size_t)(b * H + h) * R + r];
  }
  __syncthreads();

  int dg = tid & 31;
  int bg = tid >> 5;
  int d = d0 + dg;
  int b0 = bg * 2;
  float acc0 = 0.f, acc1 = 0.f;
  const float* wrow = Wkv + ((size_t)(h * D + d)) * R;
  for (int i = 0; i < R; i += 4) {
    float4 w4 = *(const float4*)&wrow[i];
    float4 ca = *(const float4*)&cs[b0][i];
    float4 cb = *(const float4*)&cs[b0 + 1][i];
    acc0 += w4.x * ca.x + w4.y * ca.y + w4.z * ca.z + w4.w * ca.w;
    acc1 += w4.x * cb.x + w4.y * cb.y + w4.z * cb.z + w4.w * cb.w;
  }
  float bv = bkv[h * D + d];
  out[(size_t)b0 * HD + h * D + d]       = acc0 + bv;
  out[(size_t)(b0 + 1) * HD + h * D + d] = acc1 + bv;
}

// ---------------------------------------------------------------------------
extern "C" void kernel_launch(void* const* d_in, const int* in_sizes, int n_in,
                              void* d_out, int out_size, void* d_ws, size_t ws_size,
                              hipStream_t stream) {
  (void)in_sizes; (void)n_in; (void)out_size; (void)ws_size;
  const float* hsq = (const float*)d_in[0];
  const float* ckv = (const float*)d_in[1];
  const float* Wq  = (const float*)d_in[2];
  const float* bq  = (const float*)d_in[3];
  const float* Wkv = (const float*)d_in[4];
  const float* bkv = (const float*)d_in[5];
  float* out = (float*)d_out;

  float* ws   = (float*)d_ws;
  float* q    = ws;                          // 65536 f
  float* ctx  = q + 65536;                   // 262144 f
  float* mbuf = ctx + 262144;                // 16384 f
  float* lbuf = mbuf + 16384;                // 16384 f
  ushort* qhi  = (ushort*)(lbuf + 16384);    // 262144 us
  ushort* qlo  = qhi + 262144;               // 262144 us
  ushort* part = qlo + 262144;               // 8388608 us (16 MB)

  k_q<<<256, 512, 0, stream>>>(hsq, Wq, bq, q);
  k_qhat<<<dim3(32, 8), 256, 0, stream>>>(q, Wkv, qhi, qlo);
  k_fmha<<<dim3(B, CH), 512, 0, stream>>>(qhi, qlo, ckv, part, mbuf, lbuf);
  k_combine<<<B * H, 256, 0, stream>>>(part, mbuf, lbuf, ctx);
  k_out<<<dim3(32, 4), 256, 0, stream>>>(ctx, Wkv, bkv, out);
}